// Round 15
// baseline (360.653 us; speedup 1.0000x reference)
//
#include <hip/hip_runtime.h>
#include <hip/hip_bf16.h>
#include <math.h>

#define NN 50000
#define NE 800000
#define NEP (NE + NN)   /* edges + self loops */
#define NG 128
#define PSPLIT 16
#define NSB ((NN + 255) / 256)   /* scan blocks = 196 */

typedef unsigned short u16;
typedef __bf16 bf16x8 __attribute__((ext_vector_type(8)));
typedef float f32x4 __attribute__((ext_vector_type(4)));

#define L2E 1.4426950408889634f

__device__ __forceinline__ float eluf(float v) {
  return v > 0.0f ? v : expm1f(v);
}
__device__ __forceinline__ float bflo(unsigned u) {
  union { unsigned i; float f; } c; c.i = u << 16; return c.f;
}
__device__ __forceinline__ float bfhi(unsigned u) {
  union { unsigned i; float f; } c; c.i = u & 0xffff0000u; return c.f;
}
__device__ __forceinline__ bf16x8 load8(const u16* p) {
  union { uint4 u; bf16x8 v; } c;
  c.u = *(const uint4*)p;
  return c.v;
}

__global__ __launch_bounds__(256) void k_deg(const int* __restrict__ ei, int* __restrict__ deg) {
  int t = blockIdx.x * 256 + threadIdx.x;
  if (t >= NEP) return;
  int dst = (t < NE) ? ei[NE + t] : (t - NE);
  atomicAdd(&deg[dst], 1);
}

// ---- multi-block exclusive scan of deg -> rowptr ----
__global__ __launch_bounds__(256) void k_scan1(const int* __restrict__ deg, int* __restrict__ bsum) {
  __shared__ int red[256];
  int i = blockIdx.x * 256 + threadIdx.x;
  red[threadIdx.x] = (i < NN) ? deg[i] : 0;
  __syncthreads();
  for (int off = 128; off > 0; off >>= 1) {
    if (threadIdx.x < off) red[threadIdx.x] += red[threadIdx.x + off];
    __syncthreads();
  }
  if (threadIdx.x == 0) bsum[blockIdx.x] = red[0];
}

__global__ __launch_bounds__(256) void k_scan2(int* __restrict__ bsum) {
  __shared__ int s[256];
  int t = threadIdx.x;
  s[t] = (t < NSB) ? bsum[t] : 0;
  __syncthreads();
  for (int off = 1; off < 256; off <<= 1) {
    int v = (t >= off) ? s[t - off] : 0;
    __syncthreads();
    s[t] += v;
    __syncthreads();
  }
  if (t < NSB) bsum[t] = (t == 0) ? 0 : s[t - 1];
}

__global__ __launch_bounds__(256) void k_scan3(const int* __restrict__ deg, const int* __restrict__ bsum,
                                               int* __restrict__ rowptr) {
  __shared__ int s[256];
  int t = threadIdx.x;
  int i = blockIdx.x * 256 + t;
  s[t] = (i < NN) ? deg[i] : 0;
  __syncthreads();
  for (int off = 1; off < 256; off <<= 1) {
    int v = (t >= off) ? s[t - off] : 0;
    __syncthreads();
    s[t] += v;
    __syncthreads();
  }
  int excl = (t == 0) ? 0 : s[t - 1];
  if (i <= NN) rowptr[i] = bsum[blockIdx.x] + excl;
}

// scatter by counting deg DOWN (atomicSub): no separate fill array / memset.
// Edge order within a node's list flips - benign fp reordering of the softmax sums.
__global__ __launch_bounds__(256) void k_scatter(const int* __restrict__ ei, const int* __restrict__ rowptr,
                                                 int* __restrict__ deg, int* __restrict__ srcidx) {
  int t = blockIdx.x * 256 + threadIdx.x;
  if (t >= NEP) return;
  int src, dst;
  if (t < NE) { src = ei[t]; dst = ei[NE + t]; } else { src = t - NE; dst = src; }
  int pos = atomicSub(&deg[dst], 1) - 1;
  srcidx[rowptr[dst] + pos] = src;
}

__global__ __launch_bounds__(256) void k_cvtw(const float* __restrict__ w1, const float* __restrict__ w2,
                                              const float* __restrict__ w3, const float* __restrict__ w4,
                                              u16* __restrict__ o) {
  int t = blockIdx.x * 256 + threadIdx.x;
  if (t >= 81920) return;
  float v;
  if (t < 8192) v = w1[t];
  else if (t < 16384) v = w2[t - 8192];
  else if (t < 49152) v = w3[t - 16384];
  else v = w4[t - 49152];
  __hip_bfloat16 b = __float2bfloat16(v);
  o[t] = *(u16*)&b;
}

// ---- MFMA dual GEMM: Y = X@W^T + bias, W picked by blockIdx.z (l: bf16 out, r: f32 out)
// No LDS: fragments loaded directly from L2/L3-resident tables (m89 layouts).
// AF32: A operand read as f32 and converted inline (saves a separate cvt pass).
template <int K, bool AF32>
__global__ __launch_bounds__(256) void k_mfma(const void* __restrict__ Xin,
                                              const u16* __restrict__ Wlb, const u16* __restrict__ Wrb,
                                              const float* __restrict__ bl, const float* __restrict__ br,
                                              __hip_bfloat16* __restrict__ Yl, float* __restrict__ Yr,
                                              int dout) {
  int lane = threadIdx.x & 63;
  int wid = threadIdx.x >> 6;
  int r0 = blockIdx.x * 64 + wid * 16;
  int c0 = blockIdx.y * 64;
  bool isR = (blockIdx.z != 0);
  const u16* W = isR ? Wrb : Wlb;
  const float* bias = isR ? br : bl;

  int arow = min(r0 + (lane & 15), NN - 1);
  int koff = (lane >> 4) * 8;
  const u16*   aph = (const u16*)Xin + (size_t)arow * K + koff;
  const float* apf = (const float*)Xin + (size_t)arow * K + koff;
  const u16* bp = W + (size_t)(c0 + (lane & 15)) * K + koff;

  f32x4 acc[4] = {};
#pragma unroll
  for (int ks = 0; ks < K / 32; ++ks) {
    bf16x8 a;
    if constexpr (AF32) {
      float4 f0 = ((const float4*)(apf + ks * 32))[0];
      float4 f1 = ((const float4*)(apf + ks * 32))[1];
      a[0] = (__bf16)f0.x; a[1] = (__bf16)f0.y; a[2] = (__bf16)f0.z; a[3] = (__bf16)f0.w;
      a[4] = (__bf16)f1.x; a[5] = (__bf16)f1.y; a[6] = (__bf16)f1.z; a[7] = (__bf16)f1.w;
    } else {
      a = load8(aph + ks * 32);
    }
    bf16x8 b0 = load8(bp + ks * 32);
    bf16x8 b1 = load8(bp + 16 * K + ks * 32);
    bf16x8 b2 = load8(bp + 32 * K + ks * 32);
    bf16x8 b3 = load8(bp + 48 * K + ks * 32);
    acc[0] = __builtin_amdgcn_mfma_f32_16x16x32_bf16(a, b0, acc[0], 0, 0, 0);
    acc[1] = __builtin_amdgcn_mfma_f32_16x16x32_bf16(a, b1, acc[1], 0, 0, 0);
    acc[2] = __builtin_amdgcn_mfma_f32_16x16x32_bf16(a, b2, acc[2], 0, 0, 0);
    acc[3] = __builtin_amdgcn_mfma_f32_16x16x32_bf16(a, b3, acc[3], 0, 0, 0);
  }

  int orow = r0 + ((lane >> 4) << 2);
  int ocol = c0 + (lane & 15);
#pragma unroll
  for (int t = 0; t < 4; ++t) {
    int col = ocol + t * 16;
    float bv = bias[col];
    if (!isR) {
#pragma unroll
      for (int v = 0; v < 4; ++v) {
        int row = orow + v;
        if (row < NN) Yl[(size_t)row * dout + col] = __float2bfloat16(acc[t][v] + bv);
      }
    } else {
#pragma unroll
      for (int v = 0; v < 4; ++v) {
        int row = orow + v;
        if (row < NN) Yr[(size_t)row * dout + col] = acc[t][v] + bv;
      }
    }
  }
}

// ---- fused GATv2 edge-score + softmax + aggregation ----
// Wave per dst node (r13-measured-best layout); lane owns V = D/64 channels
// (2 L1, 4 L2); 16 lanes per head. Factored score, single accumulator:
//   lrelu(u) = 0.6u + 0.4|u|; attv = 0.4*log2e*att:
//   score*log2e = sum_c attv*(|u| + 1.5*xl) + S0,  S0 = 1.5*sum_c attv*xr
// |u| is a free VOP3 modifier; exp via raw v_exp_f32 (scores bounded ~ +-10).
// Fixed-shift softmax (m=0) - shift-invariant. srcidx read as aligned int4.
template <int D, bool OBF16>
__global__ __launch_bounds__(256) void k_fused(const int* __restrict__ rowptr, const int* __restrict__ srcidx,
                                               const u16* __restrict__ xl, const float* __restrict__ xr,
                                               const float* __restrict__ att, const float* __restrict__ bias,
                                               void* __restrict__ outv) {
  constexpr int V = D / 64;   // 2 (layer1) or 4 (layer2)
  int lane = threadIdx.x & 63;
  int node = blockIdx.x * 4 + (threadIdx.x >> 6);
  if (node >= NN) return;
  int lo = rowptr[node], hi = rowptr[node + 1];

  float xrv[V], attv[V];
  float rlin = 0.f;
#pragma unroll
  for (int q = 0; q < V; ++q) {
    attv[q] = att[lane * V + q] * (0.4f * L2E);
    xrv[q]  = xr[(size_t)node * D + lane * V + q];
    rlin = fmaf(attv[q], xrv[q], rlin);
  }
#pragma unroll
  for (int off = 1; off < 16; off <<= 1) rlin += __shfl_xor(rlin, off);
  float S0 = 1.5f * rlin;

  const unsigned* xt1 = (const unsigned*)xl;   // V==2: one dword per lane
  const uint2*    xt2 = (const uint2*)xl;      // V==4: 8B per lane

  float denom = 0.f;
  float acc[V] = {};

  auto gather = [&](int j, float* xv) {
    if constexpr (V == 2) {
      unsigned u = xt1[(size_t)j * (D / 2) + lane];
      xv[0] = bflo(u); xv[1] = bfhi(u);
    } else {
      uint2 u = xt2[(size_t)j * (D / 4) + lane];
      xv[0] = bflo(u.x); xv[1] = bfhi(u.x);
      xv[2] = bflo(u.y); xv[3] = bfhi(u.y);
    }
  };
  auto score1 = [&](const float* xv) {
    float p = 0.f;
#pragma unroll
    for (int q = 0; q < V; ++q) {
      float u = xv[q] + xrv[q];
      float t = fmaf(1.5f, xv[q], fabsf(u));
      p = fmaf(attv[q], t, p);
    }
    return p;
  };
  auto update = [&](float p, const float* xv) {
    float w = __builtin_amdgcn_exp2f(p + S0);
    denom += w;
#pragma unroll
    for (int q = 0; q < V; ++q) acc[q] = fmaf(w, xv[q], acc[q]);
  };
  auto single = [&](int s) {
    int j0 = srcidx[s];
    float xv0[V];
    gather(j0, xv0);
    float p0 = score1(xv0);
#pragma unroll
    for (int off = 1; off < 16; off <<= 1) p0 += __shfl_xor(p0, off);
    update(p0, xv0);
  };

  int s = lo;
  int pre = min((4 - (lo & 3)) & 3, hi - lo);
  for (int k = 0; k < pre; ++k, ++s) single(s);
  for (; s + 3 < hi; s += 4) {
    int4 j4 = *(const int4*)(srcidx + s);   // aligned: srcidx 256B-aligned, s%4==0
    float xv0[V], xv1[V], xv2[V], xv3[V];
    gather(j4.x, xv0); gather(j4.y, xv1); gather(j4.z, xv2); gather(j4.w, xv3);
    float p0 = score1(xv0);
    float p1 = score1(xv1);
    float p2 = score1(xv2);
    float p3 = score1(xv3);
#pragma unroll
    for (int off = 1; off < 16; off <<= 1) {
      p0 += __shfl_xor(p0, off);
      p1 += __shfl_xor(p1, off);
      p2 += __shfl_xor(p2, off);
      p3 += __shfl_xor(p3, off);
    }
    update(p0, xv0); update(p1, xv1); update(p2, xv2); update(p3, xv3);
  }
  for (; s < hi; ++s) single(s);

  float rd = 1.0f / denom;
  float vals[V];
#pragma unroll
  for (int q = 0; q < V; ++q) vals[q] = eluf(fmaf(acc[q], rd, bias[lane * V + q]));

  if constexpr (OBF16) {
    __hip_bfloat16 tmp[V];
#pragma unroll
    for (int q = 0; q < V; ++q) tmp[q] = __float2bfloat16(vals[q]);
    if constexpr (V == 2) ((unsigned*)outv)[(size_t)node * (D / 2) + lane] = *(unsigned*)tmp;
    else                  ((uint2*)outv)[(size_t)node * (D / 4) + lane] = *(uint2*)tmp;
  } else {
    if constexpr (V == 2) {
      float2 f = {vals[0], vals[1]};
      ((float2*)outv)[(size_t)node * (D / 2) + lane] = f;
    } else {
      float4 f = {vals[0], vals[1], vals[2], vals[3]};
      ((float4*)outv)[(size_t)node * (D / 4) + lane] = f;
    }
  }
}

__device__ __forceinline__ int lowerb(const int* __restrict__ a, int n, int v) {
  int lo = 0, hi = n;
  while (lo < hi) { int mid = (lo + hi) >> 1; if (a[mid] < v) lo = mid + 1; else hi = mid; }
  return lo;
}

// ---- two-stage mean pool ----
__global__ __launch_bounds__(256) void k_pool(const float* __restrict__ h2, const int* __restrict__ batch,
                                              float* __restrict__ pooled_p) {
  int g = blockIdx.x, sp = blockIdx.y, t = threadIdx.x;
  __shared__ int sh[2];
  if (t < 2) sh[t] = lowerb(batch, NN, g + t);
  __syncthreads();
  int lo = sh[0], hi = sh[1];
  int cnt = hi - lo;
  int chunk = (cnt + PSPLIT - 1) / PSPLIT;
  int b = lo + sp * chunk;
  int e = min(b + chunk, hi);
  float acc = 0.f;
  for (int n = b; n < e; ++n) acc += h2[(size_t)n * 256 + t];
  pooled_p[((size_t)g * PSPLIT + sp) * 256 + t] = acc;
}

__global__ __launch_bounds__(128) void k_cls(const float* __restrict__ pooled_p, const int* __restrict__ batch,
                                             const float* __restrict__ Wf1, const float* __restrict__ bf1,
                                             const float* __restrict__ Wf2, const float* __restrict__ bf2,
                                             float* __restrict__ out) {
  __shared__ float p[256];
  __shared__ float z[128];
  __shared__ int sh[2];
  int g = blockIdx.x, t = threadIdx.x;
  if (t < 2) sh[t] = lowerb(batch, NN, g + t);
  __syncthreads();
  float cnt = (float)(sh[1] - sh[0]);
  float rinv = 1.0f / fmaxf(cnt, 1.0f);
  const float* pp = pooled_p + (size_t)g * PSPLIT * 256;
#pragma unroll 1
  for (int c = t; c < 256; c += 128) {
    float s = 0.f;
#pragma unroll
    for (int sp = 0; sp < PSPLIT; ++sp) s += pp[sp * 256 + c];
    p[c] = s * rinv;
  }
  __syncthreads();
  float a = bf1[t];
  const float* wr = Wf1 + (size_t)t * 256;
  for (int k = 0; k < 256; ++k) a += p[k] * wr[k];
  z[t] = fmaxf(a, 0.f);
  __syncthreads();
  if (t < 8) {
    float o = bf2[t];
    const float* w2 = Wf2 + t * 128;
    for (int k = 0; k < 128; ++k) o += z[k] * w2[k];
    out[g * 8 + t] = o;
  }
}

extern "C" void kernel_launch(void* const* d_in, const int* in_sizes, int n_in,
                              void* d_out, int out_size, void* d_ws, size_t ws_size,
                              hipStream_t stream) {
  const float* x     = (const float*)d_in[0];
  const int*   ei    = (const int*)d_in[1];
  const int*   batch = (const int*)d_in[2];
  const float* Wl1 = (const float*)d_in[3];
  const float* bl1 = (const float*)d_in[4];
  const float* Wr1 = (const float*)d_in[5];
  const float* br1 = (const float*)d_in[6];
  const float* att1  = (const float*)d_in[7];
  const float* bias1 = (const float*)d_in[8];
  const float* Wl2 = (const float*)d_in[9];
  const float* bl2 = (const float*)d_in[10];
  const float* Wr2 = (const float*)d_in[11];
  const float* br2 = (const float*)d_in[12];
  const float* att2  = (const float*)d_in[13];
  const float* bias2 = (const float*)d_in[14];
  const float* Wf1 = (const float*)d_in[15];
  const float* bf1 = (const float*)d_in[16];
  const float* Wf2 = (const float*)d_in[17];
  const float* bf2 = (const float*)d_in[18];
  float* out = (float*)d_out;

  char* w = (char*)d_ws;
  size_t off = 0;
  auto alloc = [&](size_t bytes) -> void* {
    void* p = w + off;
    off += (bytes + 255) & ~(size_t)255;
    return p;
  };
  int* rowptr = (int*)alloc((NN + 1) * sizeof(int));
  int* deg    = (int*)alloc(NN * sizeof(int));
  int* bsum   = (int*)alloc(NSB * sizeof(int));
  int* srcidx = (int*)alloc((size_t)NEP * sizeof(int));
  u16* Wb     = (u16*)alloc((size_t)81920 * sizeof(u16));       // all 4 W in bf16
  u16* Wl1b = Wb, *Wr1b = Wb + 8192, *Wl2b = Wb + 16384, *Wr2b = Wb + 49152;
  // region A: xl1(bf16 12.8MB) + xr1(f32 25.6MB), later reused for xl2(bf16 25.6MB)
  char* regA  = (char*)alloc((size_t)NN * 128 * 2 + (size_t)NN * 128 * 4);
  __hip_bfloat16* xl1 = (__hip_bfloat16*)regA;
  float*          xr1 = (float*)(regA + (size_t)NN * 128 * 2);
  __hip_bfloat16* xl2 = (__hip_bfloat16*)regA;          // overlays xl1+xr1 (dead by then)
  u16*   h1b    = (u16*)alloc((size_t)NN * 128 * sizeof(u16)); // h1 in bf16 (layer-2 A)
  float* xr2    = (float*)alloc((size_t)NN * 256 * sizeof(float));
  float* h2     = xr2;   // in-place: each node reads its xr row before writing
  float* pooled_p = (float*)alloc((size_t)NG * PSPLIT * 256 * sizeof(float));
  (void)ws_size; (void)in_sizes; (void)n_in; (void)out_size;

  hipMemsetAsync(deg, 0, NN * sizeof(int), stream);

  const int EB = (NEP + 255) / 256;
  k_deg<<<EB, 256, 0, stream>>>(ei, deg);
  k_scan1<<<NSB, 256, 0, stream>>>(deg, bsum);
  k_scan2<<<1, 256, 0, stream>>>(bsum);
  k_scan3<<<NSB, 256, 0, stream>>>(deg, bsum, rowptr);
  k_scatter<<<EB, 256, 0, stream>>>(ei, rowptr, deg, srcidx);   // consumes deg (countdown)

  k_cvtw<<<(81920 + 255) / 256, 256, 0, stream>>>(Wl1, Wr1, Wl2, Wr2, Wb);

  const int RB = (NN + 63) / 64;
  // ---- layer 1 (64 -> 4x32) ----
  dim3 g1(RB, 2, 2);
  k_mfma<64, true><<<g1, 256, 0, stream>>>(x, Wl1b, Wr1b, bl1, br1, xl1, xr1, 128);
  k_fused<128, true><<<(NN + 3) / 4, 256, 0, stream>>>(rowptr, srcidx, (const u16*)xl1, xr1,
                                                       att1, bias1, h1b);

  // ---- layer 2 (128 -> 4x64) ----
  dim3 g2(RB, 4, 2);
  k_mfma<128, false><<<g2, 256, 0, stream>>>(h1b, Wl2b, Wr2b, bl2, br2, xl2, xr2, 256);
  k_fused<256, false><<<(NN + 3) / 4, 256, 0, stream>>>(rowptr, srcidx, (const u16*)xl2, xr2,
                                                        att2, bias2, h2);

  // ---- pool + classifier ----
  dim3 gp(NG, PSPLIT);
  k_pool<<<gp, 256, 0, stream>>>(h2, batch, pooled_p);
  k_cls<<<NG, 128, 0, stream>>>(pooled_p, batch, Wf1, bf1, Wf2, bf2, out);
}

// Round 16
// 347.918 us; speedup vs baseline: 1.0366x; 1.0366x over previous
//
#include <hip/hip_runtime.h>
#include <hip/hip_bf16.h>
#include <math.h>

#define NN 50000
#define NE 800000
#define NEP (NE + NN)   /* edges + self loops */
#define NG 128
#define PSPLIT 16
#define NSB ((NN + 255) / 256)   /* scan blocks = 196 */

typedef unsigned short u16;
typedef __bf16 bf16x8 __attribute__((ext_vector_type(8)));
typedef float f32x4 __attribute__((ext_vector_type(4)));

#define L2E 1.4426950408889634f

__device__ __forceinline__ float eluf(float v) {
  return v > 0.0f ? v : expm1f(v);
}
__device__ __forceinline__ float bflo(unsigned u) {
  union { unsigned i; float f; } c; c.i = u << 16; return c.f;
}
__device__ __forceinline__ float bfhi(unsigned u) {
  union { unsigned i; float f; } c; c.i = u & 0xffff0000u; return c.f;
}
__device__ __forceinline__ bf16x8 load8(const u16* p) {
  union { uint4 u; bf16x8 v; } c;
  c.u = *(const uint4*)p;
  return c.v;
}

__global__ __launch_bounds__(256) void k_deg(const int* __restrict__ ei, int* __restrict__ deg) {
  int t = blockIdx.x * 256 + threadIdx.x;
  if (t >= NEP) return;
  int dst = (t < NE) ? ei[NE + t] : (t - NE);
  atomicAdd(&deg[dst], 1);
}

// ---- multi-block exclusive scan of deg -> rowptr ----
__global__ __launch_bounds__(256) void k_scan1(const int* __restrict__ deg, int* __restrict__ bsum) {
  __shared__ int red[256];
  int i = blockIdx.x * 256 + threadIdx.x;
  red[threadIdx.x] = (i < NN) ? deg[i] : 0;
  __syncthreads();
  for (int off = 128; off > 0; off >>= 1) {
    if (threadIdx.x < off) red[threadIdx.x] += red[threadIdx.x + off];
    __syncthreads();
  }
  if (threadIdx.x == 0) bsum[blockIdx.x] = red[0];
}

__global__ __launch_bounds__(256) void k_scan2(int* __restrict__ bsum) {
  __shared__ int s[256];
  int t = threadIdx.x;
  s[t] = (t < NSB) ? bsum[t] : 0;
  __syncthreads();
  for (int off = 1; off < 256; off <<= 1) {
    int v = (t >= off) ? s[t - off] : 0;
    __syncthreads();
    s[t] += v;
    __syncthreads();
  }
  if (t < NSB) bsum[t] = (t == 0) ? 0 : s[t - 1];
}

__global__ __launch_bounds__(256) void k_scan3(const int* __restrict__ deg, const int* __restrict__ bsum,
                                               int* __restrict__ rowptr) {
  __shared__ int s[256];
  int t = threadIdx.x;
  int i = blockIdx.x * 256 + t;
  s[t] = (i < NN) ? deg[i] : 0;
  __syncthreads();
  for (int off = 1; off < 256; off <<= 1) {
    int v = (t >= off) ? s[t - off] : 0;
    __syncthreads();
    s[t] += v;
    __syncthreads();
  }
  int excl = (t == 0) ? 0 : s[t - 1];
  if (i <= NN) rowptr[i] = bsum[blockIdx.x] + excl;
}

__global__ __launch_bounds__(256) void k_scatter(const int* __restrict__ ei, const int* __restrict__ rowptr,
                                                 int* __restrict__ fill, int* __restrict__ srcidx) {
  int t = blockIdx.x * 256 + threadIdx.x;
  if (t >= NEP) return;
  int src, dst;
  if (t < NE) { src = ei[t]; dst = ei[NE + t]; } else { src = t - NE; dst = src; }
  int pos = atomicAdd(&fill[dst], 1);
  srcidx[rowptr[dst] + pos] = src;
}

__global__ __launch_bounds__(256) void k_cvtw(const float* __restrict__ w1, const float* __restrict__ w2,
                                              const float* __restrict__ w3, const float* __restrict__ w4,
                                              u16* __restrict__ o) {
  int t = blockIdx.x * 256 + threadIdx.x;
  if (t >= 81920) return;
  float v;
  if (t < 8192) v = w1[t];
  else if (t < 16384) v = w2[t - 8192];
  else if (t < 49152) v = w3[t - 16384];
  else v = w4[t - 49152];
  __hip_bfloat16 b = __float2bfloat16(v);
  o[t] = *(u16*)&b;
}

// ---- MFMA dual GEMM: Y = X@W^T + bias, W picked by blockIdx.z (l: bf16 out, r: f32 out)
// No LDS: fragments loaded directly from L2/L3-resident tables (m89 layouts).
// AF32: A operand read as f32 and converted inline (saves a separate cvt pass;
// identical RNE rounding to a separate cvt kernel).
template <int K, bool AF32>
__global__ __launch_bounds__(256) void k_mfma(const void* __restrict__ Xin,
                                              const u16* __restrict__ Wlb, const u16* __restrict__ Wrb,
                                              const float* __restrict__ bl, const float* __restrict__ br,
                                              __hip_bfloat16* __restrict__ Yl, float* __restrict__ Yr,
                                              int dout) {
  int lane = threadIdx.x & 63;
  int wid = threadIdx.x >> 6;
  int r0 = blockIdx.x * 64 + wid * 16;
  int c0 = blockIdx.y * 64;
  bool isR = (blockIdx.z != 0);
  const u16* W = isR ? Wrb : Wlb;
  const float* bias = isR ? br : bl;

  int arow = min(r0 + (lane & 15), NN - 1);
  int koff = (lane >> 4) * 8;
  const u16*   aph = (const u16*)Xin + (size_t)arow * K + koff;
  const float* apf = (const float*)Xin + (size_t)arow * K + koff;
  const u16* bp = W + (size_t)(c0 + (lane & 15)) * K + koff;

  f32x4 acc[4] = {};
#pragma unroll
  for (int ks = 0; ks < K / 32; ++ks) {
    bf16x8 a;
    if constexpr (AF32) {
      float4 f0 = ((const float4*)(apf + ks * 32))[0];
      float4 f1 = ((const float4*)(apf + ks * 32))[1];
      a[0] = (__bf16)f0.x; a[1] = (__bf16)f0.y; a[2] = (__bf16)f0.z; a[3] = (__bf16)f0.w;
      a[4] = (__bf16)f1.x; a[5] = (__bf16)f1.y; a[6] = (__bf16)f1.z; a[7] = (__bf16)f1.w;
    } else {
      a = load8(aph + ks * 32);
    }
    bf16x8 b0 = load8(bp + ks * 32);
    bf16x8 b1 = load8(bp + 16 * K + ks * 32);
    bf16x8 b2 = load8(bp + 32 * K + ks * 32);
    bf16x8 b3 = load8(bp + 48 * K + ks * 32);
    acc[0] = __builtin_amdgcn_mfma_f32_16x16x32_bf16(a, b0, acc[0], 0, 0, 0);
    acc[1] = __builtin_amdgcn_mfma_f32_16x16x32_bf16(a, b1, acc[1], 0, 0, 0);
    acc[2] = __builtin_amdgcn_mfma_f32_16x16x32_bf16(a, b2, acc[2], 0, 0, 0);
    acc[3] = __builtin_amdgcn_mfma_f32_16x16x32_bf16(a, b3, acc[3], 0, 0, 0);
  }

  int orow = r0 + ((lane >> 4) << 2);
  int ocol = c0 + (lane & 15);
#pragma unroll
  for (int t = 0; t < 4; ++t) {
    int col = ocol + t * 16;
    float bv = bias[col];
    if (!isR) {
#pragma unroll
      for (int v = 0; v < 4; ++v) {
        int row = orow + v;
        if (row < NN) Yl[(size_t)row * dout + col] = __float2bfloat16(acc[t][v] + bv);
      }
    } else {
#pragma unroll
      for (int v = 0; v < 4; ++v) {
        int row = orow + v;
        if (row < NN) Yr[(size_t)row * dout + col] = acc[t][v] + bv;
      }
    }
  }
}

// ---- fused GATv2 edge-score + softmax + aggregation (r13-measured-best form) ----
// Wave per dst node; lane owns V = D/64 channels (2 L1, 4 L2); 16 lanes per head.
// Factored score with TWO accumulators (ILP - r15 lesson: single-acc serialized
// the chain and lost 14% VALUBusy):
//   lrelu(u) = 0.6u + 0.4|u|; attv = 0.4*log2e*att:
//   score*log2e = sum(attv*|u|) + 1.5*sum(attv*xl) + S0,  S0 = 1.5*sum(attv*xr)
// Gather addressing: 32-bit byte offsets via shifts (strides are pow2) - avoids
// 64-bit mul chains per gather. Fixed-shift softmax (m=0), shift-invariant.
template <int D, bool OBF16>
__global__ __launch_bounds__(256) void k_fused(const int* __restrict__ rowptr, const int* __restrict__ srcidx,
                                               const u16* __restrict__ xl, const float* __restrict__ xr,
                                               const float* __restrict__ att, const float* __restrict__ bias,
                                               void* __restrict__ outv) {
  constexpr int V = D / 64;              // 2 (layer1) or 4 (layer2)
  constexpr int SH = (V == 2) ? 8 : 9;   // row stride in bytes: 256 / 512
  int lane = threadIdx.x & 63;
  int node = blockIdx.x * 4 + (threadIdx.x >> 6);
  if (node >= NN) return;
  int lo = rowptr[node], hi = rowptr[node + 1];

  float xrv[V], attv[V];
  float rlin = 0.f;
#pragma unroll
  for (int q = 0; q < V; ++q) {
    attv[q] = att[lane * V + q] * (0.4f * L2E);
    xrv[q]  = xr[(size_t)node * D + lane * V + q];
    rlin = fmaf(attv[q], xrv[q], rlin);
  }
#pragma unroll
  for (int off = 1; off < 16; off <<= 1) rlin += __shfl_xor(rlin, off);
  float S0 = 1.5f * rlin;

  const char* xb = (const char*)xl;
  unsigned lb = (unsigned)lane << (SH - 6);   // lane*4 (V=2) or lane*8 (V=4)

  float denom = 0.f;
  float acc[V] = {};

  auto gather = [&](int j, float* xv) {
    unsigned off = ((unsigned)j << SH) + lb;
    if constexpr (V == 2) {
      unsigned u = *(const unsigned*)(xb + off);
      xv[0] = bflo(u); xv[1] = bfhi(u);
    } else {
      uint2 u = *(const uint2*)(xb + off);
      xv[0] = bflo(u.x); xv[1] = bfhi(u.x);
      xv[2] = bflo(u.y); xv[3] = bfhi(u.y);
    }
  };
  auto score2 = [&](const float* xv) {
    float pa = 0.f, pl = 0.f;
#pragma unroll
    for (int q = 0; q < V; ++q) {
      float u = xv[q] + xrv[q];
      pa = fmaf(attv[q], fabsf(u), pa);
      pl = fmaf(attv[q], xv[q], pl);
    }
    return fmaf(pl, 1.5f, pa);
  };
  auto update = [&](float p, const float* xv) {
    float w = exp2f(p + S0);
    denom += w;
#pragma unroll
    for (int q = 0; q < V; ++q) acc[q] = fmaf(w, xv[q], acc[q]);
  };

  int s = lo;
  for (; s + 3 < hi; s += 4) {
    int j0 = srcidx[s], j1 = srcidx[s + 1], j2 = srcidx[s + 2], j3 = srcidx[s + 3];
    float xv0[V], xv1[V], xv2[V], xv3[V];
    gather(j0, xv0); gather(j1, xv1); gather(j2, xv2); gather(j3, xv3);
    float p0 = score2(xv0);
    float p1 = score2(xv1);
    float p2 = score2(xv2);
    float p3 = score2(xv3);
#pragma unroll
    for (int off = 1; off < 16; off <<= 1) {
      p0 += __shfl_xor(p0, off);
      p1 += __shfl_xor(p1, off);
      p2 += __shfl_xor(p2, off);
      p3 += __shfl_xor(p3, off);
    }
    update(p0, xv0); update(p1, xv1); update(p2, xv2); update(p3, xv3);
  }
  for (; s < hi; ++s) {
    int j0 = srcidx[s];
    float xv0[V];
    gather(j0, xv0);
    float p0 = score2(xv0);
#pragma unroll
    for (int off = 1; off < 16; off <<= 1) p0 += __shfl_xor(p0, off);
    update(p0, xv0);
  }

  float rd = 1.0f / denom;
  float vals[V];
#pragma unroll
  for (int q = 0; q < V; ++q) vals[q] = eluf(fmaf(acc[q], rd, bias[lane * V + q]));

  if constexpr (OBF16) {
    __hip_bfloat16 tmp[V];
#pragma unroll
    for (int q = 0; q < V; ++q) tmp[q] = __float2bfloat16(vals[q]);
    if constexpr (V == 2) ((unsigned*)outv)[(size_t)node * (D / 2) + lane] = *(unsigned*)tmp;
    else                  ((uint2*)outv)[(size_t)node * (D / 4) + lane] = *(uint2*)tmp;
  } else {
    if constexpr (V == 2) {
      float2 f = {vals[0], vals[1]};
      ((float2*)outv)[(size_t)node * (D / 2) + lane] = f;
    } else {
      float4 f = {vals[0], vals[1], vals[2], vals[3]};
      ((float4*)outv)[(size_t)node * (D / 4) + lane] = f;
    }
  }
}

__device__ __forceinline__ int lowerb(const int* __restrict__ a, int n, int v) {
  int lo = 0, hi = n;
  while (lo < hi) { int mid = (lo + hi) >> 1; if (a[mid] < v) lo = mid + 1; else hi = mid; }
  return lo;
}

// ---- two-stage mean pool ----
__global__ __launch_bounds__(256) void k_pool(const float* __restrict__ h2, const int* __restrict__ batch,
                                              float* __restrict__ pooled_p) {
  int g = blockIdx.x, sp = blockIdx.y, t = threadIdx.x;
  __shared__ int sh[2];
  if (t < 2) sh[t] = lowerb(batch, NN, g + t);
  __syncthreads();
  int lo = sh[0], hi = sh[1];
  int cnt = hi - lo;
  int chunk = (cnt + PSPLIT - 1) / PSPLIT;
  int b = lo + sp * chunk;
  int e = min(b + chunk, hi);
  float acc = 0.f;
  for (int n = b; n < e; ++n) acc += h2[(size_t)n * 256 + t];
  pooled_p[((size_t)g * PSPLIT + sp) * 256 + t] = acc;
}

__global__ __launch_bounds__(128) void k_cls(const float* __restrict__ pooled_p, const int* __restrict__ batch,
                                             const float* __restrict__ Wf1, const float* __restrict__ bf1,
                                             const float* __restrict__ Wf2, const float* __restrict__ bf2,
                                             float* __restrict__ out) {
  __shared__ float p[256];
  __shared__ float z[128];
  __shared__ int sh[2];
  int g = blockIdx.x, t = threadIdx.x;
  if (t < 2) sh[t] = lowerb(batch, NN, g + t);
  __syncthreads();
  float cnt = (float)(sh[1] - sh[0]);
  float rinv = 1.0f / fmaxf(cnt, 1.0f);
  const float* pp = pooled_p + (size_t)g * PSPLIT * 256;
#pragma unroll 1
  for (int c = t; c < 256; c += 128) {
    float s = 0.f;
#pragma unroll
    for (int sp = 0; sp < PSPLIT; ++sp) s += pp[sp * 256 + c];
    p[c] = s * rinv;
  }
  __syncthreads();
  float a = bf1[t];
  const float* wr = Wf1 + (size_t)t * 256;
  for (int k = 0; k < 256; ++k) a += p[k] * wr[k];
  z[t] = fmaxf(a, 0.f);
  __syncthreads();
  if (t < 8) {
    float o = bf2[t];
    const float* w2 = Wf2 + t * 128;
    for (int k = 0; k < 128; ++k) o += z[k] * w2[k];
    out[g * 8 + t] = o;
  }
}

extern "C" void kernel_launch(void* const* d_in, const int* in_sizes, int n_in,
                              void* d_out, int out_size, void* d_ws, size_t ws_size,
                              hipStream_t stream) {
  const float* x     = (const float*)d_in[0];
  const int*   ei    = (const int*)d_in[1];
  const int*   batch = (const int*)d_in[2];
  const float* Wl1 = (const float*)d_in[3];
  const float* bl1 = (const float*)d_in[4];
  const float* Wr1 = (const float*)d_in[5];
  const float* br1 = (const float*)d_in[6];
  const float* att1  = (const float*)d_in[7];
  const float* bias1 = (const float*)d_in[8];
  const float* Wl2 = (const float*)d_in[9];
  const float* bl2 = (const float*)d_in[10];
  const float* Wr2 = (const float*)d_in[11];
  const float* br2 = (const float*)d_in[12];
  const float* att2  = (const float*)d_in[13];
  const float* bias2 = (const float*)d_in[14];
  const float* Wf1 = (const float*)d_in[15];
  const float* bf1 = (const float*)d_in[16];
  const float* Wf2 = (const float*)d_in[17];
  const float* bf2 = (const float*)d_in[18];
  float* out = (float*)d_out;

  char* w = (char*)d_ws;
  size_t off = 0;
  auto alloc = [&](size_t bytes) -> void* {
    void* p = w + off;
    off += (bytes + 255) & ~(size_t)255;
    return p;
  };
  int* rowptr = (int*)alloc((NN + 1) * sizeof(int));
  int* deg    = (int*)alloc(NN * sizeof(int));
  int* fill   = (int*)alloc(NN * sizeof(int));
  int* bsum   = (int*)alloc(NSB * sizeof(int));
  int* srcidx = (int*)alloc((size_t)NEP * sizeof(int));
  u16* Wb     = (u16*)alloc((size_t)81920 * sizeof(u16));       // all 4 W in bf16
  u16* Wl1b = Wb, *Wr1b = Wb + 8192, *Wl2b = Wb + 16384, *Wr2b = Wb + 49152;
  // region A: xl1(bf16 12.8MB) + xr1(f32 25.6MB), later reused for xl2(bf16 25.6MB)
  char* regA  = (char*)alloc((size_t)NN * 128 * 2 + (size_t)NN * 128 * 4);
  __hip_bfloat16* xl1 = (__hip_bfloat16*)regA;
  float*          xr1 = (float*)(regA + (size_t)NN * 128 * 2);
  __hip_bfloat16* xl2 = (__hip_bfloat16*)regA;          // overlays xl1+xr1 (dead by then)
  u16*   h1b    = (u16*)alloc((size_t)NN * 128 * sizeof(u16)); // h1 in bf16 (layer-2 A)
  float* xr2    = (float*)alloc((size_t)NN * 256 * sizeof(float));
  float* h2     = xr2;   // in-place: each node reads its xr row before writing
  float* pooled_p = (float*)alloc((size_t)NG * PSPLIT * 256 * sizeof(float));
  (void)ws_size; (void)in_sizes; (void)n_in; (void)out_size;

  hipMemsetAsync(deg, 0, NN * sizeof(int), stream);
  hipMemsetAsync(fill, 0, NN * sizeof(int), stream);

  const int EB = (NEP + 255) / 256;
  k_deg<<<EB, 256, 0, stream>>>(ei, deg);
  k_scan1<<<NSB, 256, 0, stream>>>(deg, bsum);
  k_scan2<<<1, 256, 0, stream>>>(bsum);
  k_scan3<<<NSB, 256, 0, stream>>>(deg, bsum, rowptr);
  k_scatter<<<EB, 256, 0, stream>>>(ei, rowptr, fill, srcidx);

  k_cvtw<<<(81920 + 255) / 256, 256, 0, stream>>>(Wl1, Wr1, Wl2, Wr2, Wb);

  const int RB = (NN + 63) / 64;
  // ---- layer 1 (64 -> 4x32) ----
  dim3 g1(RB, 2, 2);
  k_mfma<64, true><<<g1, 256, 0, stream>>>(x, Wl1b, Wr1b, bl1, br1, xl1, xr1, 128);
  k_fused<128, true><<<(NN + 3) / 4, 256, 0, stream>>>(rowptr, srcidx, (const u16*)xl1, xr1,
                                                       att1, bias1, h1b);

  // ---- layer 2 (128 -> 4x64) ----
  dim3 g2(RB, 4, 2);
  k_mfma<128, false><<<g2, 256, 0, stream>>>(h1b, Wl2b, Wr2b, bl2, br2, xl2, xr2, 256);
  k_fused<256, false><<<(NN + 3) / 4, 256, 0, stream>>>(rowptr, srcidx, (const u16*)xl2, xr2,
                                                        att2, bias2, h2);

  // ---- pool + classifier ----
  dim3 gp(NG, PSPLIT);
  k_pool<<<gp, 256, 0, stream>>>(h2, batch, pooled_p);
  k_cls<<<NG, 128, 0, stream>>>(pooled_p, batch, Wf1, bf1, Wf2, bf2, out);
}

// Round 17
// 345.702 us; speedup vs baseline: 1.0432x; 1.0064x over previous
//
#include <hip/hip_runtime.h>
#include <hip/hip_bf16.h>
#include <math.h>

#define NN 50000
#define NE 800000
#define NEP (NE + NN)   /* edges + self loops */
#define NG 128
#define PSPLIT 16
#define NSB ((NN + 255) / 256)   /* scan blocks = 196 */

typedef unsigned short u16;
typedef __bf16 bf16x8 __attribute__((ext_vector_type(8)));
typedef float f32x4 __attribute__((ext_vector_type(4)));

#define L2E 1.4426950408889634f

__device__ __forceinline__ float eluf(float v) {
  return v > 0.0f ? v : expm1f(v);
}
__device__ __forceinline__ float bflo(unsigned u) {
  union { unsigned i; float f; } c; c.i = u << 16; return c.f;
}
__device__ __forceinline__ float bfhi(unsigned u) {
  union { unsigned i; float f; } c; c.i = u & 0xffff0000u; return c.f;
}
__device__ __forceinline__ bf16x8 load8(const u16* p) {
  union { uint4 u; bf16x8 v; } c;
  c.u = *(const uint4*)p;
  return c.v;
}

__global__ __launch_bounds__(256) void k_deg(const int* __restrict__ ei, int* __restrict__ deg) {
  int t = blockIdx.x * 256 + threadIdx.x;
  if (t >= NEP) return;
  int dst = (t < NE) ? ei[NE + t] : (t - NE);
  atomicAdd(&deg[dst], 1);
}

// ---- multi-block exclusive scan of deg -> rowptr ----
__global__ __launch_bounds__(256) void k_scan1(const int* __restrict__ deg, int* __restrict__ bsum) {
  __shared__ int red[256];
  int i = blockIdx.x * 256 + threadIdx.x;
  red[threadIdx.x] = (i < NN) ? deg[i] : 0;
  __syncthreads();
  for (int off = 128; off > 0; off >>= 1) {
    if (threadIdx.x < off) red[threadIdx.x] += red[threadIdx.x + off];
    __syncthreads();
  }
  if (threadIdx.x == 0) bsum[blockIdx.x] = red[0];
}

__global__ __launch_bounds__(256) void k_scan2(int* __restrict__ bsum) {
  __shared__ int s[256];
  int t = threadIdx.x;
  s[t] = (t < NSB) ? bsum[t] : 0;
  __syncthreads();
  for (int off = 1; off < 256; off <<= 1) {
    int v = (t >= off) ? s[t - off] : 0;
    __syncthreads();
    s[t] += v;
    __syncthreads();
  }
  if (t < NSB) bsum[t] = (t == 0) ? 0 : s[t - 1];
}

__global__ __launch_bounds__(256) void k_scan3(const int* __restrict__ deg, const int* __restrict__ bsum,
                                               int* __restrict__ rowptr) {
  __shared__ int s[256];
  int t = threadIdx.x;
  int i = blockIdx.x * 256 + t;
  s[t] = (i < NN) ? deg[i] : 0;
  __syncthreads();
  for (int off = 1; off < 256; off <<= 1) {
    int v = (t >= off) ? s[t - off] : 0;
    __syncthreads();
    s[t] += v;
    __syncthreads();
  }
  int excl = (t == 0) ? 0 : s[t - 1];
  if (i <= NN) rowptr[i] = bsum[blockIdx.x] + excl;
}

__global__ __launch_bounds__(256) void k_scatter(const int* __restrict__ ei, const int* __restrict__ rowptr,
                                                 int* __restrict__ fill, int* __restrict__ srcidx) {
  int t = blockIdx.x * 256 + threadIdx.x;
  if (t >= NEP) return;
  int src, dst;
  if (t < NE) { src = ei[t]; dst = ei[NE + t]; } else { src = t - NE; dst = src; }
  int pos = atomicAdd(&fill[dst], 1);
  srcidx[rowptr[dst] + pos] = src;
}

__global__ __launch_bounds__(256) void k_cvtw(const float* __restrict__ w1, const float* __restrict__ w2,
                                              const float* __restrict__ w3, const float* __restrict__ w4,
                                              u16* __restrict__ o) {
  int t = blockIdx.x * 256 + threadIdx.x;
  if (t >= 81920) return;
  float v;
  if (t < 8192) v = w1[t];
  else if (t < 16384) v = w2[t - 8192];
  else if (t < 49152) v = w3[t - 16384];
  else v = w4[t - 49152];
  __hip_bfloat16 b = __float2bfloat16(v);
  o[t] = *(u16*)&b;
}

// ---- MFMA dual GEMM: Y = X@W^T + bias, W picked by blockIdx.z (l: bf16 out, r: f32 out)
// No LDS: fragments loaded directly from L2/L3-resident tables (m89 layouts).
// AF32: A operand read as f32 and converted inline.
template <int K, bool AF32>
__global__ __launch_bounds__(256) void k_mfma(const void* __restrict__ Xin,
                                              const u16* __restrict__ Wlb, const u16* __restrict__ Wrb,
                                              const float* __restrict__ bl, const float* __restrict__ br,
                                              __hip_bfloat16* __restrict__ Yl, float* __restrict__ Yr,
                                              int dout) {
  int lane = threadIdx.x & 63;
  int wid = threadIdx.x >> 6;
  int r0 = blockIdx.x * 64 + wid * 16;
  int c0 = blockIdx.y * 64;
  bool isR = (blockIdx.z != 0);
  const u16* W = isR ? Wrb : Wlb;
  const float* bias = isR ? br : bl;

  int arow = min(r0 + (lane & 15), NN - 1);
  int koff = (lane >> 4) * 8;
  const u16*   aph = (const u16*)Xin + (size_t)arow * K + koff;
  const float* apf = (const float*)Xin + (size_t)arow * K + koff;
  const u16* bp = W + (size_t)(c0 + (lane & 15)) * K + koff;

  f32x4 acc[4] = {};
#pragma unroll
  for (int ks = 0; ks < K / 32; ++ks) {
    bf16x8 a;
    if constexpr (AF32) {
      float4 f0 = ((const float4*)(apf + ks * 32))[0];
      float4 f1 = ((const float4*)(apf + ks * 32))[1];
      a[0] = (__bf16)f0.x; a[1] = (__bf16)f0.y; a[2] = (__bf16)f0.z; a[3] = (__bf16)f0.w;
      a[4] = (__bf16)f1.x; a[5] = (__bf16)f1.y; a[6] = (__bf16)f1.z; a[7] = (__bf16)f1.w;
    } else {
      a = load8(aph + ks * 32);
    }
    bf16x8 b0 = load8(bp + ks * 32);
    bf16x8 b1 = load8(bp + 16 * K + ks * 32);
    bf16x8 b2 = load8(bp + 32 * K + ks * 32);
    bf16x8 b3 = load8(bp + 48 * K + ks * 32);
    acc[0] = __builtin_amdgcn_mfma_f32_16x16x32_bf16(a, b0, acc[0], 0, 0, 0);
    acc[1] = __builtin_amdgcn_mfma_f32_16x16x32_bf16(a, b1, acc[1], 0, 0, 0);
    acc[2] = __builtin_amdgcn_mfma_f32_16x16x32_bf16(a, b2, acc[2], 0, 0, 0);
    acc[3] = __builtin_amdgcn_mfma_f32_16x16x32_bf16(a, b3, acc[3], 0, 0, 0);
  }

  int orow = r0 + ((lane >> 4) << 2);
  int ocol = c0 + (lane & 15);
#pragma unroll
  for (int t = 0; t < 4; ++t) {
    int col = ocol + t * 16;
    float bv = bias[col];
    if (!isR) {
#pragma unroll
      for (int v = 0; v < 4; ++v) {
        int row = orow + v;
        if (row < NN) Yl[(size_t)row * dout + col] = __float2bfloat16(acc[t][v] + bv);
      }
    } else {
#pragma unroll
      for (int v = 0; v < 4; ++v) {
        int row = orow + v;
        if (row < NN) Yr[(size_t)row * dout + col] = acc[t][v] + bv;
      }
    }
  }
}

// ---- layer-1 fused kernel: 2 edges per wave ----
// D=128: lanes 0-31 = edge A, 32-63 = edge B (il = lane&31, sub = lane>>5);
// lane owns channels [il*4, il*4+4); head = il>>3 (8 lanes/head) -> 3-step tree
// serving 2 edges. Same factored two-accumulator score as the proven form.
// Tail: phantom edge gets w = 0. Final cross-half combine: 5 shuffles/node.
__global__ __launch_bounds__(256) void k_fused1(const int* __restrict__ rowptr, const int* __restrict__ srcidx,
                                                const u16* __restrict__ xl, const float* __restrict__ xr,
                                                const float* __restrict__ att, const float* __restrict__ bias,
                                                u16* __restrict__ outv) {
  int lane = threadIdx.x & 63;
  int node = blockIdx.x * 4 + (threadIdx.x >> 6);
  if (node >= NN) return;
  int il = lane & 31, sub = lane >> 5;
  int lo = rowptr[node], hi = rowptr[node + 1];

  float xrv[4], attv[4];
  float rlin = 0.f;
#pragma unroll
  for (int q = 0; q < 4; ++q) {
    attv[q] = att[il * 4 + q] * (0.4f * L2E);
    xrv[q]  = xr[(size_t)node * 128 + il * 4 + q];
    rlin = fmaf(attv[q], xrv[q], rlin);
  }
#pragma unroll
  for (int off = 1; off < 8; off <<= 1) rlin += __shfl_xor(rlin, off);
  float S0 = 1.5f * rlin;

  const char* xb = (const char*)xl;
  unsigned lb = (unsigned)il << 3;   // il*8 bytes

  float denom = 0.f;
  float acc[4] = {};

  auto gather = [&](int j, float* xv) {
    uint2 u = *(const uint2*)(xb + (((unsigned)j << 8) + lb));
    xv[0] = bflo(u.x); xv[1] = bfhi(u.x);
    xv[2] = bflo(u.y); xv[3] = bfhi(u.y);
  };
  auto score2 = [&](const float* xv) {
    float pa = 0.f, pl = 0.f;
#pragma unroll
    for (int q = 0; q < 4; ++q) {
      float u = xv[q] + xrv[q];
      pa = fmaf(attv[q], fabsf(u), pa);
      pl = fmaf(attv[q], xv[q], pl);
    }
    return fmaf(pl, 1.5f, pa);
  };
  auto update = [&](float p, const float* xv) {
    float w = exp2f(p + S0);
    denom += w;
#pragma unroll
    for (int q = 0; q < 4; ++q) acc[q] = fmaf(w, xv[q], acc[q]);
  };

  int s = lo;
  for (; s + 3 < hi; s += 4) {            // 4 edges per iteration (2 per half)
    int j0 = srcidx[s + sub];
    int j1 = srcidx[s + 2 + sub];
    float xv0[4], xv1[4];
    gather(j0, xv0); gather(j1, xv1);
    float p0 = score2(xv0);
    float p1 = score2(xv1);
#pragma unroll
    for (int off = 1; off < 8; off <<= 1) {
      p0 += __shfl_xor(p0, off);
      p1 += __shfl_xor(p1, off);
    }
    update(p0, xv0); update(p1, xv1);
  }
  for (; s < hi; s += 2) {                // tail: 2 edges (phantom-masked)
    int e = s + sub;
    bool valid = e < hi;
    int j = srcidx[valid ? e : lo];
    float xv[4];
    gather(j, xv);
    float p = score2(xv);
#pragma unroll
    for (int off = 1; off < 8; off <<= 1) p += __shfl_xor(p, off);
    float w = valid ? exp2f(p + S0) : 0.f;
    denom += w;
#pragma unroll
    for (int q = 0; q < 4; ++q) acc[q] = fmaf(w, xv[q], acc[q]);
  }

  // combine halves
  denom += __shfl_xor(denom, 32);
#pragma unroll
  for (int q = 0; q < 4; ++q) acc[q] += __shfl_xor(acc[q], 32);

  if (sub == 0) {
    float rd = 1.0f / denom;
    __hip_bfloat16 tmp[4];
#pragma unroll
    for (int q = 0; q < 4; ++q)
      tmp[q] = __float2bfloat16(eluf(fmaf(acc[q], rd, bias[il * 4 + q])));
    ((uint2*)outv)[(size_t)node * 32 + il] = *(uint2*)tmp;
  }
}

// ---- layer-2 fused kernel (r13/r16-measured-best form, unchanged) ----
// Wave per dst node; lane owns V = 4 channels; 16 lanes per head.
// Two-accumulator factored score (ILP), 32-bit shift addressing.
template <int D, bool OBF16>
__global__ __launch_bounds__(256) void k_fused(const int* __restrict__ rowptr, const int* __restrict__ srcidx,
                                               const u16* __restrict__ xl, const float* __restrict__ xr,
                                               const float* __restrict__ att, const float* __restrict__ bias,
                                               void* __restrict__ outv) {
  constexpr int V = D / 64;              // 4 (layer2)
  constexpr int SH = (V == 2) ? 8 : 9;   // row stride in bytes
  int lane = threadIdx.x & 63;
  int node = blockIdx.x * 4 + (threadIdx.x >> 6);
  if (node >= NN) return;
  int lo = rowptr[node], hi = rowptr[node + 1];

  float xrv[V], attv[V];
  float rlin = 0.f;
#pragma unroll
  for (int q = 0; q < V; ++q) {
    attv[q] = att[lane * V + q] * (0.4f * L2E);
    xrv[q]  = xr[(size_t)node * D + lane * V + q];
    rlin = fmaf(attv[q], xrv[q], rlin);
  }
#pragma unroll
  for (int off = 1; off < 16; off <<= 1) rlin += __shfl_xor(rlin, off);
  float S0 = 1.5f * rlin;

  const char* xb = (const char*)xl;
  unsigned lb = (unsigned)lane << (SH - 6);

  float denom = 0.f;
  float acc[V] = {};

  auto gather = [&](int j, float* xv) {
    unsigned off = ((unsigned)j << SH) + lb;
    if constexpr (V == 2) {
      unsigned u = *(const unsigned*)(xb + off);
      xv[0] = bflo(u); xv[1] = bfhi(u);
    } else {
      uint2 u = *(const uint2*)(xb + off);
      xv[0] = bflo(u.x); xv[1] = bfhi(u.x);
      xv[2] = bflo(u.y); xv[3] = bfhi(u.y);
    }
  };
  auto score2 = [&](const float* xv) {
    float pa = 0.f, pl = 0.f;
#pragma unroll
    for (int q = 0; q < V; ++q) {
      float u = xv[q] + xrv[q];
      pa = fmaf(attv[q], fabsf(u), pa);
      pl = fmaf(attv[q], xv[q], pl);
    }
    return fmaf(pl, 1.5f, pa);
  };
  auto update = [&](float p, const float* xv) {
    float w = exp2f(p + S0);
    denom += w;
#pragma unroll
    for (int q = 0; q < V; ++q) acc[q] = fmaf(w, xv[q], acc[q]);
  };

  int s = lo;
  for (; s + 3 < hi; s += 4) {
    int j0 = srcidx[s], j1 = srcidx[s + 1], j2 = srcidx[s + 2], j3 = srcidx[s + 3];
    float xv0[V], xv1[V], xv2[V], xv3[V];
    gather(j0, xv0); gather(j1, xv1); gather(j2, xv2); gather(j3, xv3);
    float p0 = score2(xv0);
    float p1 = score2(xv1);
    float p2 = score2(xv2);
    float p3 = score2(xv3);
#pragma unroll
    for (int off = 1; off < 16; off <<= 1) {
      p0 += __shfl_xor(p0, off);
      p1 += __shfl_xor(p1, off);
      p2 += __shfl_xor(p2, off);
      p3 += __shfl_xor(p3, off);
    }
    update(p0, xv0); update(p1, xv1); update(p2, xv2); update(p3, xv3);
  }
  for (; s < hi; ++s) {
    int j0 = srcidx[s];
    float xv0[V];
    gather(j0, xv0);
    float p0 = score2(xv0);
#pragma unroll
    for (int off = 1; off < 16; off <<= 1) p0 += __shfl_xor(p0, off);
    update(p0, xv0);
  }

  float rd = 1.0f / denom;
  float vals[V];
#pragma unroll
  for (int q = 0; q < V; ++q) vals[q] = eluf(fmaf(acc[q], rd, bias[lane * V + q]));

  if constexpr (OBF16) {
    __hip_bfloat16 tmp[V];
#pragma unroll
    for (int q = 0; q < V; ++q) tmp[q] = __float2bfloat16(vals[q]);
    if constexpr (V == 2) ((unsigned*)outv)[(size_t)node * (D / 2) + lane] = *(unsigned*)tmp;
    else                  ((uint2*)outv)[(size_t)node * (D / 4) + lane] = *(uint2*)tmp;
  } else {
    if constexpr (V == 2) {
      float2 f = {vals[0], vals[1]};
      ((float2*)outv)[(size_t)node * (D / 2) + lane] = f;
    } else {
      float4 f = {vals[0], vals[1], vals[2], vals[3]};
      ((float4*)outv)[(size_t)node * (D / 4) + lane] = f;
    }
  }
}

__device__ __forceinline__ int lowerb(const int* __restrict__ a, int n, int v) {
  int lo = 0, hi = n;
  while (lo < hi) { int mid = (lo + hi) >> 1; if (a[mid] < v) lo = mid + 1; else hi = mid; }
  return lo;
}

// ---- two-stage mean pool ----
__global__ __launch_bounds__(256) void k_pool(const float* __restrict__ h2, const int* __restrict__ batch,
                                              float* __restrict__ pooled_p) {
  int g = blockIdx.x, sp = blockIdx.y, t = threadIdx.x;
  __shared__ int sh[2];
  if (t < 2) sh[t] = lowerb(batch, NN, g + t);
  __syncthreads();
  int lo = sh[0], hi = sh[1];
  int cnt = hi - lo;
  int chunk = (cnt + PSPLIT - 1) / PSPLIT;
  int b = lo + sp * chunk;
  int e = min(b + chunk, hi);
  float acc = 0.f;
  for (int n = b; n < e; ++n) acc += h2[(size_t)n * 256 + t];
  pooled_p[((size_t)g * PSPLIT + sp) * 256 + t] = acc;
}

__global__ __launch_bounds__(128) void k_cls(const float* __restrict__ pooled_p, const int* __restrict__ batch,
                                             const float* __restrict__ Wf1, const float* __restrict__ bf1,
                                             const float* __restrict__ Wf2, const float* __restrict__ bf2,
                                             float* __restrict__ out) {
  __shared__ float p[256];
  __shared__ float z[128];
  __shared__ int sh[2];
  int g = blockIdx.x, t = threadIdx.x;
  if (t < 2) sh[t] = lowerb(batch, NN, g + t);
  __syncthreads();
  float cnt = (float)(sh[1] - sh[0]);
  float rinv = 1.0f / fmaxf(cnt, 1.0f);
  const float* pp = pooled_p + (size_t)g * PSPLIT * 256;
#pragma unroll 1
  for (int c = t; c < 256; c += 128) {
    float s = 0.f;
#pragma unroll
    for (int sp = 0; sp < PSPLIT; ++sp) s += pp[sp * 256 + c];
    p[c] = s * rinv;
  }
  __syncthreads();
  float a = bf1[t];
  const float* wr = Wf1 + (size_t)t * 256;
  for (int k = 0; k < 256; ++k) a += p[k] * wr[k];
  z[t] = fmaxf(a, 0.f);
  __syncthreads();
  if (t < 8) {
    float o = bf2[t];
    const float* w2 = Wf2 + t * 128;
    for (int k = 0; k < 128; ++k) o += z[k] * w2[k];
    out[g * 8 + t] = o;
  }
}

extern "C" void kernel_launch(void* const* d_in, const int* in_sizes, int n_in,
                              void* d_out, int out_size, void* d_ws, size_t ws_size,
                              hipStream_t stream) {
  const float* x     = (const float*)d_in[0];
  const int*   ei    = (const int*)d_in[1];
  const int*   batch = (const int*)d_in[2];
  const float* Wl1 = (const float*)d_in[3];
  const float* bl1 = (const float*)d_in[4];
  const float* Wr1 = (const float*)d_in[5];
  const float* br1 = (const float*)d_in[6];
  const float* att1  = (const float*)d_in[7];
  const float* bias1 = (const float*)d_in[8];
  const float* Wl2 = (const float*)d_in[9];
  const float* bl2 = (const float*)d_in[10];
  const float* Wr2 = (const float*)d_in[11];
  const float* br2 = (const float*)d_in[12];
  const float* att2  = (const float*)d_in[13];
  const float* bias2 = (const float*)d_in[14];
  const float* Wf1 = (const float*)d_in[15];
  const float* bf1 = (const float*)d_in[16];
  const float* Wf2 = (const float*)d_in[17];
  const float* bf2 = (const float*)d_in[18];
  float* out = (float*)d_out;

  char* w = (char*)d_ws;
  size_t off = 0;
  auto alloc = [&](size_t bytes) -> void* {
    void* p = w + off;
    off += (bytes + 255) & ~(size_t)255;
    return p;
  };
  int* rowptr = (int*)alloc((NN + 1) * sizeof(int));
  int* deg    = (int*)alloc(NN * sizeof(int));
  int* fill   = (int*)alloc(NN * sizeof(int));
  int* bsum   = (int*)alloc(NSB * sizeof(int));
  int* srcidx = (int*)alloc((size_t)NEP * sizeof(int));
  u16* Wb     = (u16*)alloc((size_t)81920 * sizeof(u16));       // all 4 W in bf16
  u16* Wl1b = Wb, *Wr1b = Wb + 8192, *Wl2b = Wb + 16384, *Wr2b = Wb + 49152;
  // region A: xl1(bf16 12.8MB) + xr1(f32 25.6MB), later reused for xl2(bf16 25.6MB)
  char* regA  = (char*)alloc((size_t)NN * 128 * 2 + (size_t)NN * 128 * 4);
  __hip_bfloat16* xl1 = (__hip_bfloat16*)regA;
  float*          xr1 = (float*)(regA + (size_t)NN * 128 * 2);
  __hip_bfloat16* xl2 = (__hip_bfloat16*)regA;          // overlays xl1+xr1 (dead by then)
  u16*   h1b    = (u16*)alloc((size_t)NN * 128 * sizeof(u16)); // h1 in bf16 (layer-2 A)
  float* xr2    = (float*)alloc((size_t)NN * 256 * sizeof(float));
  float* h2     = xr2;   // in-place: each node reads its xr row before writing
  float* pooled_p = (float*)alloc((size_t)NG * PSPLIT * 256 * sizeof(float));
  (void)ws_size; (void)in_sizes; (void)n_in; (void)out_size;

  hipMemsetAsync(deg, 0, NN * sizeof(int), stream);
  hipMemsetAsync(fill, 0, NN * sizeof(int), stream);

  const int EB = (NEP + 255) / 256;
  k_deg<<<EB, 256, 0, stream>>>(ei, deg);
  k_scan1<<<NSB, 256, 0, stream>>>(deg, bsum);
  k_scan2<<<1, 256, 0, stream>>>(bsum);
  k_scan3<<<NSB, 256, 0, stream>>>(deg, bsum, rowptr);
  k_scatter<<<EB, 256, 0, stream>>>(ei, rowptr, fill, srcidx);

  k_cvtw<<<(81920 + 255) / 256, 256, 0, stream>>>(Wl1, Wr1, Wl2, Wr2, Wb);

  const int RB = (NN + 63) / 64;
  // ---- layer 1 (64 -> 4x32) ----
  dim3 g1(RB, 2, 2);
  k_mfma<64, true><<<g1, 256, 0, stream>>>(x, Wl1b, Wr1b, bl1, br1, xl1, xr1, 128);
  k_fused1<<<(NN + 3) / 4, 256, 0, stream>>>(rowptr, srcidx, (const u16*)xl1, xr1,
                                             att1, bias1, h1b);

  // ---- layer 2 (128 -> 4x64) ----
  dim3 g2(RB, 4, 2);
  k_mfma<128, false><<<g2, 256, 0, stream>>>(h1b, Wl2b, Wr2b, bl2, br2, xl2, xr2, 256);
  k_fused<256, false><<<(NN + 3) / 4, 256, 0, stream>>>(rowptr, srcidx, (const u16*)xl2, xr2,
                                                        att2, bias2, h2);

  // ---- pool + classifier ----
  dim3 gp(NG, PSPLIT);
  k_pool<<<gp, 256, 0, stream>>>(h2, batch, pooled_p);
  k_cls<<<NG, 128, 0, stream>>>(pooled_p, batch, Wf1, bf1, Wf2, bf2, out);
}